// Round 17
// baseline (458.691 us; speedup 1.0000x reference)
//
#include <hip/hip_runtime.h>

// ---------------------------------------------------------------------------
// DWT autoencoder round trip. Level-2 dwt2+idwt2 cancel exactly -> LL1r==LL1.
//   K0: rearrange conv weights into consumption order + zero-page
//   K1: wave-independent (no barriers) 4x64 y-tile per wave, lane = column.
//       acc[4][9] register blocking -> 4 pixel-rows per 81-weight fetch
//       (fixes the 1:1 FMA:weight-fetch ratio that pinned 13 k1 variants at
//       ~60us; k2's 4:1 ratio runs 45% VALUBusy). Band rows computed ONCE
//       (v-sweep), no launch_bounds VGPR cap (R8/R11/R12 spills were caps).
//   K2: convT4x4 s2 of y -> l1 bands, fused with idwt2(LL1, l1) -> out
// B=32, C=3, H=W=512.
// ---------------------------------------------------------------------------

#define BB 32

__global__ __launch_bounds__(256) void k0_rearrange(
    const float* __restrict__ dw, const float* __restrict__ uw,
    float* __restrict__ wd, float* __restrict__ wu, float* __restrict__ zp)
{
    const int t = threadIdx.x;
    for (int i = t; i < 729; i += 256) {
        const int o    = i % 9;
        const int band = (i / 9) % 3;
        const int q    = (i / 27) % 3;
        const int a    = (i / 81) % 3;
        const int ch   = i / 243;
        wd[i] = 0.5f * dw[o * 81 + (ch * 3 + band) * 9 + a * 3 + q];
    }
    for (int i = t; i < 1296; i += 256) {
        const int o = i % 9; int r = i / 9;
        const int dj = r & 1; const int di = (r >> 1) & 1; r >>= 2;
        const int ct = r & 1; const int rt = (r >> 1) & 1; const int cin = r >> 2;
        wu[i] = uw[cin * 144 + o * 16 + (3 - di - 2 * rt) * 4 + (3 - dj - 2 * ct)];
    }
    if (t < 16) zp[t] = 0.f;
}

__device__ __forceinline__ void gload16(const float* gp, float* lp) {
    __builtin_amdgcn_global_load_lds(
        (const __attribute__((address_space(1))) void*)gp,
        (__attribute__((address_space(3))) void*)lp, 16, 0, 0);
}

// K1: one wave = y rows I0..I0+3, cols J0..J0+63. Lane l owns col J0+l.
// Band row v (0..8), global r = 2*I0-1+v, feeds pixel row rc where
// a = v-2rc in [0,2]. x tile per ch: 18 rows x 65 f4 = 1170 slots (pad 1216,
// 19 full-wave gload rounds; invalid lanes read the zero-page, junk lands in
// pad slots never read). LDS 19.0KB -> 8 waves/CU; 2048 waves all resident.
__global__ __launch_bounds__(64) void k1_dwt_down(
    const float* __restrict__ x,     // (B,3,512,512)
    const float* __restrict__ wd,    // reordered (ch,a,q,band,o), x0.5 folded
    const float* __restrict__ db,    // (9)
    const float* __restrict__ zp,    // 16-float zero page
    float* __restrict__ LL1,         // (B,3,256,256)
    float* __restrict__ y)           // (B,9,128,128)
{
    __shared__ float xs[4864];       // 1216 f4 slots (1170 used), 19.46 KB

    const int l    = threadIdx.x;                     // lane 0..63
    const int bid  = blockIdx.x;                      // 0..2047
    const int swz  = (bid & 7) * 256 + (bid >> 3);    // XCD-contiguous chunks
    const int b    = swz >> 6;                        // image 0..31
    const int tin  = swz & 63;
    const int I0   = (tin >> 1) * 4;                  // y row origin 0..124
    const int J0   = (tin & 1) * 64;                  // y col origin {0,64}
    const int gr0  = 4 * I0 - 2;                      // x row of LDS row 0
    const int gc0  = 4 * J0 - 4;                      // x col of LDS f4 col 0

    float acc[4][9];
#pragma unroll
    for (int rc = 0; rc < 4; ++rc)
#pragma unroll
        for (int o = 0; o < 9; ++o) acc[rc][o] = db[o];

#pragma unroll
    for (int ch = 0; ch < 3; ++ch) {
        const float* xc = x + ((size_t)b * 3 + ch) * (512 * 512);
        if (ch) {   // previous channel's ds_reads must finish before overwrite
            asm volatile("s_waitcnt lgkmcnt(0)" ::: "memory");
            __builtin_amdgcn_sched_barrier(0);
        }
        // ---- stage this channel: 19 full-wave gload rounds ----
#pragma unroll
        for (int n = 0; n < 19; ++n) {
            const int idx = n * 64 + l;               // 0..1215
            const int lr  = idx / 65;
            const int f4c = idx - lr * 65;
            const int gr  = gr0 + lr;
            const bool ok = (idx < 1170) && (gr >= 0) && !(f4c == 0 && J0 == 0);
            const float* gp = ok ? (xc + (size_t)gr * 512 + gc0 + 4 * f4c) : zp;
            gload16(gp, &xs[idx * 4]);
        }
        asm volatile("s_waitcnt vmcnt(0)" ::: "memory");
        __builtin_amdgcn_sched_barrier(0);

        const float* wch = wd + ch * 243;
        float* llc = LL1 + ((size_t)b * 3 + ch) * (256 * 256);

        // ---- v-sweep: 9 band rows, each computed once ----
#pragma unroll
        for (int v = 0; v < 9; ++v) {
            float2 pA[3], pB[3];
#pragma unroll
            for (int k = 0; k < 3; ++k) {
                pA[k] = *reinterpret_cast<const float2*>(
                    &xs[(2 * v) * 260 + 4 * l + 2 + 2 * k]);
                pB[k] = *reinterpret_cast<const float2*>(
                    &xs[(2 * v + 1) * 260 + 4 * l + 2 + 2 * k]);
            }
            float lh[3], hl[3], hh[3], llv1, llv2;
            {
                const float s0 = pA[0].x + pA[0].y, d0 = pA[0].x - pA[0].y;
                const float s1 = pB[0].x + pB[0].y, d1 = pB[0].x - pB[0].y;
                lh[0] = s0 - s1; hl[0] = d0 + d1; hh[0] = d0 - d1;
            }
            {
                const float s0 = pA[1].x + pA[1].y, d0 = pA[1].x - pA[1].y;
                const float s1 = pB[1].x + pB[1].y, d1 = pB[1].x - pB[1].y;
                lh[1] = s0 - s1; hl[1] = d0 + d1; hh[1] = d0 - d1;
                llv1 = (s0 + s1) * 0.5f;
            }
            {
                const float s0 = pA[2].x + pA[2].y, d0 = pA[2].x - pA[2].y;
                const float s1 = pB[2].x + pB[2].y, d1 = pB[2].x - pB[2].y;
                lh[2] = s0 - s1; hl[2] = d0 + d1; hh[2] = d0 - d1;
                llv2 = (s0 + s1) * 0.5f;
            }

            // LL1: tile owns ll rows 2*I0..2*I0+7 <=> v in [1,8]; coalesced f2
            if (v >= 1) {
                const int rg = 2 * I0 - 1 + v;
                float2 w2; w2.x = llv1; w2.y = llv2;
                *reinterpret_cast<float2*>(
                    llc + (size_t)rg * 256 + 2 * (J0 + l)) = w2;
            }

            // FMA into pixel rows rc with a = v-2rc (compile-time folds)
#pragma unroll
            for (int rc = 0; rc < 4; ++rc) {
                const int a = v - 2 * rc;
                if (a >= 0 && a <= 2) {
                    const float* wg = wch + a * 81;
#pragma unroll
                    for (int q = 0; q < 3; ++q) {
                        const float* w0 = wg + q * 27;   // 27 consecutive
                        const float vlh = lh[q], vhl = hl[q], vhh = hh[q];
#pragma unroll
                        for (int o = 0; o < 9; ++o) acc[rc][o] += vlh * w0[o];
#pragma unroll
                        for (int o = 0; o < 9; ++o) acc[rc][o] += vhl * w0[9 + o];
#pragma unroll
                        for (int o = 0; o < 9; ++o) acc[rc][o] += vhh * w0[18 + o];
                    }
                }
            }
        }
    }

    // y stores: fully coalesced (64 lanes x 4B contiguous per (rc,o))
#pragma unroll
    for (int rc = 0; rc < 4; ++rc)
#pragma unroll
        for (int o = 0; o < 9; ++o)
            y[(((size_t)b * 9 + o) * 128 + (I0 + rc)) * 128 + J0 + l] = acc[rc][o];
}

// K2: one block = one batch image, a 32x32 tile at 256-res (=> 64x64 output
// pixels at 512-res), all 3 colors. Each thread owns a 2x2 parity quad; all
// 36 accumulators live (needs VGPR room -> launch_bounds(256,4)).
__global__ __launch_bounds__(256, 4) void k2_up_idwt(
    const float* __restrict__ yg,    // (B,9,128,128)
    const float* __restrict__ wu,    // reordered (cin,rt,ct,di,dj,o)
    const float* __restrict__ ub,    // (9)
    const float* __restrict__ LL1,   // (B,3,256,256)
    float* __restrict__ out)         // (B,3,512,512)
{
    __shared__ float ysh[9][18][19];

    const int t    = threadIdx.x;
    const int b    = blockIdx.x >> 6;
    const int tile = blockIdx.x & 63;
    const int r0   = (tile >> 3) << 5;  // 256-res tile origin
    const int c0   = (tile & 7) << 5;
    const int p0   = (r0 >> 1) - 1;     // y row of local 0
    const int q0   = (c0 >> 1) - 1;

    // ---- stage y tile (18x18 halo, 9 ch) into LDS ----
    for (int item = t; item < 9 * 324; item += 256) {
        const int cin = item / 324;
        int rem       = item - cin * 324;
        const int lp  = rem / 18;
        const int lq  = rem - lp * 18;
        const int p   = p0 + lp, q = q0 + lq;
        float v = 0.f;
        if (p >= 0 && p < 128 && q >= 0 && q < 128)
            v = yg[(((size_t)b * 9 + cin) * 128 + p) * 128 + q];
        ysh[cin][lp][lq] = v;
    }
    __syncthreads();

    const int i2 = t >> 4;   // 0..15
    const int j2 = t & 15;   // 0..15

    float acc[2][2][9];      // [di][dj][out-ch]
#pragma unroll
    for (int di = 0; di < 2; ++di)
#pragma unroll
        for (int dj = 0; dj < 2; ++dj)
#pragma unroll
            for (int o = 0; o < 9; ++o) acc[di][dj][o] = ub[o];

    for (int cin = 0; cin < 9; ++cin) {
        float yv[3][3];
#pragma unroll
        for (int r = 0; r < 3; ++r)
#pragma unroll
            for (int c = 0; c < 3; ++c)
                yv[r][c] = ysh[cin][i2 + r][j2 + c];
        const float* wc = wu + cin * 144;
#pragma unroll
        for (int rt = 0; rt < 2; ++rt)
#pragma unroll
            for (int ct = 0; ct < 2; ++ct) {
                const float* wg = wc + (rt * 2 + ct) * 36;  // 36 consecutive
#pragma unroll
                for (int di = 0; di < 2; ++di)
#pragma unroll
                    for (int dj = 0; dj < 2; ++dj) {
                        const float vv = yv[di + rt][dj + ct];
                        const float* w9 = wg + (di * 2 + dj) * 9;
#pragma unroll
                        for (int o = 0; o < 9; ++o)
                            acc[di][dj][o] += vv * w9[o];
                    }
            }
    }

    // ---- epilogue: idwt2(LL1, LH, HL, HH) -> 4x4 output pixels / color ----
#pragma unroll
    for (int cc = 0; cc < 3; ++cc) {
#pragma unroll
        for (int di = 0; di < 2; ++di) {
            const int I = r0 + 2 * i2 + di;
            const int J = c0 + 2 * j2;
            const float2 llv = *reinterpret_cast<const float2*>(
                LL1 + (((size_t)b * 3 + cc) * 256 + I) * 256 + J);
            float4 top, bot;
            {
                const float ll = llv.x;
                const float lh = acc[di][0][cc * 3 + 0];
                const float hl = acc[di][0][cc * 3 + 1];
                const float hh = acc[di][0][cc * 3 + 2];
                const float e0 = ll + lh, od0 = ll - lh;
                const float e1 = hl + hh, od1 = hl - hh;
                top.x = (e0 + e1) * 0.5f; top.y = (e0 - e1) * 0.5f;
                bot.x = (od0 + od1) * 0.5f; bot.y = (od0 - od1) * 0.5f;
            }
            {
                const float ll = llv.y;
                const float lh = acc[di][1][cc * 3 + 0];
                const float hl = acc[di][1][cc * 3 + 1];
                const float hh = acc[di][1][cc * 3 + 2];
                const float e0 = ll + lh, od0 = ll - lh;
                const float e1 = hl + hh, od1 = hl - hh;
                top.z = (e0 + e1) * 0.5f; top.w = (e0 - e1) * 0.5f;
                bot.z = (od0 + od1) * 0.5f; bot.w = (od0 - od1) * 0.5f;
            }
            float* op = out + (((size_t)b * 3 + cc) * 512 + 2 * I) * 512 + 2 * J;
            *reinterpret_cast<float4*>(op) = top;
            *reinterpret_cast<float4*>(op + 512) = bot;
        }
    }
}

extern "C" void kernel_launch(void* const* d_in, const int* in_sizes, int n_in,
                              void* d_out, int out_size, void* d_ws, size_t ws_size,
                              hipStream_t stream) {
    const float* x  = (const float*)d_in[0];
    const float* dw = (const float*)d_in[1];
    const float* db = (const float*)d_in[2];
    const float* uw = (const float*)d_in[3];
    const float* ub = (const float*)d_in[4];
    float* outp = (float*)d_out;

    float* wsf = (float*)d_ws;
    float* wd  = wsf;            // 729 floats (pad to 768)
    float* wu  = wsf + 768;      // 1296 floats
    float* zp  = wsf + 2240;     // 16-float zero page (16B aligned)
    float* LL1 = wsf + 2304;                         // 25.2 MB
    float* y   = LL1 + (size_t)BB * 3 * 256 * 256;   // 18.9 MB

    k0_rearrange<<<dim3(1), dim3(256), 0, stream>>>(dw, uw, wd, wu, zp);
    k1_dwt_down<<<dim3(2048), dim3(64), 0, stream>>>(x, wd, db, zp, LL1, y);
    k2_up_idwt<<<dim3(BB * 64), dim3(256), 0, stream>>>(y, wu, ub, LL1, outp);
}

// Round 18
// 85.293 us; speedup vs baseline: 5.3778x; 5.3778x over previous
//
#include <hip/hip_runtime.h>

// ---------------------------------------------------------------------------
// DWT autoencoder round trip. Level-2 dwt2+idwt2 cancel exactly -> LL1r==LL1.
//   K0: rearrange conv weights into consumption order
//   K1: k2's EXACT skeleton applied to the down path. 8x16 y-tile/block:
//       stage = compute 9 band planes (17x33) into 20.2KB LDS with plain
//       coalesced float2 x loads (+inline LL1 writes), ONE barrier, then
//       k2-shaped conv (9 cin x 9 ds_reads x 45/36 FMAs, og wave-split).
//       7 blocks/CU -> 87% occupancy cap (R3 = same skeleton @39KB = 50% cap
//       ran 60us at 38% -- this tests the occupancy cell of that matrix).
//   K2: convT4x4 s2 of y -> l1 bands, fused with idwt2(LL1, l1) -> out
// B=32, C=3, H=W=512.
// R17 lesson: acc[4][9]+full-unroll -> VGPR 208, 2 waves/SIMD, 506us.
// Working-kernel pattern (k2): small LDS, one barrier, scalar stage loads,
// modest per-thread state. Mimic it exactly.
// ---------------------------------------------------------------------------

#define BB 32

// K0: wd[(cin*9 + a*3 + q)*9 + o] = 0.5 * dw[o, cin, a, q]   (cin = ch*3+band)
//     wu[((cin*4+rt*2+ct)*4+di*2+dj)*9+o] = uw[cin, o, 3-di-2rt, 3-dj-2ct]
__global__ __launch_bounds__(256) void k0_rearrange(
    const float* __restrict__ dw, const float* __restrict__ uw,
    float* __restrict__ wd, float* __restrict__ wu)
{
    const int t = threadIdx.x;
    for (int i = t; i < 729; i += 256) {
        const int o   = i % 9;
        const int q   = (i / 9) % 3;
        const int a   = (i / 27) % 3;
        const int cin = i / 81;
        wd[i] = 0.5f * dw[o * 81 + cin * 9 + a * 3 + q];
    }
    for (int i = t; i < 1296; i += 256) {
        const int o = i % 9; int r = i / 9;
        const int dj = r & 1; const int di = (r >> 1) & 1; r >>= 2;
        const int ct = r & 1; const int rt = (r >> 1) & 1; const int cin = r >> 2;
        wu[i] = uw[cin * 144 + o * 16 + (3 - di - 2 * rt) * 4 + (3 - dj - 2 * ct)];
    }
}

// K1: block = 8x16 y-tile. Stage: 1683 items (3ch x 17x33 band grid), each
// reads a 2x2 x-block (two float2, coalesced over lc), writes 3 band planes
// to LDS + owned LL1 interior. One barrier. Conv: t = (og, pixel); og=0 wave
// pair does outputs 0-4, og=1 does 5-8 (wave-uniform). 9 cin x 9 ds_reads.
__global__ __launch_bounds__(256) void k1_dwt_down(
    const float* __restrict__ x,     // (B,3,512,512)
    const float* __restrict__ wd,    // reordered (cin,a,q,o), x0.5 folded
    const float* __restrict__ db,    // (9)
    float* __restrict__ LL1,         // (B,3,256,256)
    float* __restrict__ y)           // (B,9,128,128)
{
    __shared__ float bnd[9 * 561];   // plane (ch*3+band): 17 x 33, 20.2 KB

    const int t   = threadIdx.x;
    const int bid = blockIdx.x;                     // 0..4095
    const int swz = (bid & 7) * 512 + (bid >> 3);   // XCD-contiguous chunks
    const int b   = swz >> 7;                       // image 0..31
    const int tin = swz & 127;
    const int I0  = (tin >> 3) * 8;                 // y row origin (0..120)
    const int J0  = (tin & 7) * 16;                 // y col origin (0..112)

    // ---- stage: bands + LL1 (plain coalesced loads, like k2's stage) ----
    for (int it = t; it < 1683; it += 256) {
        const int ch = it / 561;
        const int rc = it - ch * 561;
        const int lr = rc / 33;                     // 0..16
        const int lc = rc - lr * 33;                // 0..32
        const int rB = 2 * I0 - 1 + lr;             // band row, -1..254
        const int cB = 2 * J0 - 1 + lc;             // band col, -1..254
        float x00 = 0.f, x01 = 0.f, x10 = 0.f, x11 = 0.f;
        if (rB >= 0 && cB >= 0) {
            const float* xp =
                x + (((size_t)b * 3 + ch) * 512 + 2 * rB) * 512 + 2 * cB;
            const float2 v0 = *reinterpret_cast<const float2*>(xp);
            const float2 v1 = *reinterpret_cast<const float2*>(xp + 512);
            x00 = v0.x; x01 = v0.y; x10 = v1.x; x11 = v1.y;
        }
        const float s0 = x00 + x01, d0 = x00 - x01;
        const float s1 = x10 + x11, d1 = x10 - x11;
        bnd[(ch * 3 + 0) * 561 + lr * 33 + lc] = s0 - s1;   // lh
        bnd[(ch * 3 + 1) * 561 + lr * 33 + lc] = d0 + d1;   // hl
        bnd[(ch * 3 + 2) * 561 + lr * 33 + lc] = d0 - d1;   // hh
        if (lr >= 1 && lc >= 1)
            LL1[(((size_t)b * 3 + ch) * 256 + rB) * 256 + cB] = (s0 + s1) * 0.5f;
    }
    __syncthreads();

    // ---- conv: k2-shaped (9 cin, 9 ds_reads, consecutive uniform weights) ----
    const int og = t >> 7;           // wave-uniform output half
    const int tl = t & 127;
    const int ti = tl >> 4;          // 0..7
    const int tj = tl & 15;          // 0..15
    const int I  = I0 + ti;
    const int J  = J0 + tj;

    if (og == 0) {
        float acc[5];
#pragma unroll
        for (int o = 0; o < 5; ++o) acc[o] = db[o];
        for (int cin = 0; cin < 9; ++cin) {
            float v[3][3];
#pragma unroll
            for (int a = 0; a < 3; ++a)
#pragma unroll
                for (int q = 0; q < 3; ++q)
                    v[a][q] = bnd[cin * 561 + (2 * ti + a) * 33 + 2 * tj + q];
            const float* wc = wd + cin * 81;
#pragma unroll
            for (int a = 0; a < 3; ++a)
#pragma unroll
                for (int q = 0; q < 3; ++q) {
                    const float vv = v[a][q];
                    const float* w9 = wc + (a * 3 + q) * 9;
#pragma unroll
                    for (int o = 0; o < 5; ++o) acc[o] += vv * w9[o];
                }
        }
#pragma unroll
        for (int o = 0; o < 5; ++o)
            y[(((size_t)b * 9 + o) * 128 + I) * 128 + J] = acc[o];
    } else {
        float acc[4];
#pragma unroll
        for (int o = 0; o < 4; ++o) acc[o] = db[5 + o];
        for (int cin = 0; cin < 9; ++cin) {
            float v[3][3];
#pragma unroll
            for (int a = 0; a < 3; ++a)
#pragma unroll
                for (int q = 0; q < 3; ++q)
                    v[a][q] = bnd[cin * 561 + (2 * ti + a) * 33 + 2 * tj + q];
            const float* wc = wd + cin * 81;
#pragma unroll
            for (int a = 0; a < 3; ++a)
#pragma unroll
                for (int q = 0; q < 3; ++q) {
                    const float vv = v[a][q];
                    const float* w9 = wc + (a * 3 + q) * 9 + 5;
#pragma unroll
                    for (int o = 0; o < 4; ++o) acc[o] += vv * w9[o];
                }
        }
#pragma unroll
        for (int o = 0; o < 4; ++o)
            y[(((size_t)b * 9 + 5 + o) * 128 + I) * 128 + J] = acc[o];
    }
}

// K2: one block = one batch image, a 32x32 tile at 256-res (=> 64x64 output
// pixels at 512-res), all 3 colors. Each thread owns a 2x2 parity quad; all
// 36 accumulators live (needs VGPR room -> launch_bounds(256,4)).
__global__ __launch_bounds__(256, 4) void k2_up_idwt(
    const float* __restrict__ yg,    // (B,9,128,128)
    const float* __restrict__ wu,    // reordered (cin,rt,ct,di,dj,o)
    const float* __restrict__ ub,    // (9)
    const float* __restrict__ LL1,   // (B,3,256,256)
    float* __restrict__ out)         // (B,3,512,512)
{
    __shared__ float ysh[9][18][19];

    const int t    = threadIdx.x;
    const int b    = blockIdx.x >> 6;
    const int tile = blockIdx.x & 63;
    const int r0   = (tile >> 3) << 5;  // 256-res tile origin
    const int c0   = (tile & 7) << 5;
    const int p0   = (r0 >> 1) - 1;     // y row of local 0
    const int q0   = (c0 >> 1) - 1;

    // ---- stage y tile (18x18 halo, 9 ch) into LDS ----
    for (int item = t; item < 9 * 324; item += 256) {
        const int cin = item / 324;
        int rem       = item - cin * 324;
        const int lp  = rem / 18;
        const int lq  = rem - lp * 18;
        const int p   = p0 + lp, q = q0 + lq;
        float v = 0.f;
        if (p >= 0 && p < 128 && q >= 0 && q < 128)
            v = yg[(((size_t)b * 9 + cin) * 128 + p) * 128 + q];
        ysh[cin][lp][lq] = v;
    }
    __syncthreads();

    const int i2 = t >> 4;   // 0..15
    const int j2 = t & 15;   // 0..15

    float acc[2][2][9];      // [di][dj][out-ch]
#pragma unroll
    for (int di = 0; di < 2; ++di)
#pragma unroll
        for (int dj = 0; dj < 2; ++dj)
#pragma unroll
            for (int o = 0; o < 9; ++o) acc[di][dj][o] = ub[o];

    for (int cin = 0; cin < 9; ++cin) {
        float yv[3][3];
#pragma unroll
        for (int r = 0; r < 3; ++r)
#pragma unroll
            for (int c = 0; c < 3; ++c)
                yv[r][c] = ysh[cin][i2 + r][j2 + c];
        const float* wc = wu + cin * 144;
#pragma unroll
        for (int rt = 0; rt < 2; ++rt)
#pragma unroll
            for (int ct = 0; ct < 2; ++ct) {
                const float* wg = wc + (rt * 2 + ct) * 36;  // 36 consecutive
#pragma unroll
                for (int di = 0; di < 2; ++di)
#pragma unroll
                    for (int dj = 0; dj < 2; ++dj) {
                        const float vv = yv[di + rt][dj + ct];
                        const float* w9 = wg + (di * 2 + dj) * 9;
#pragma unroll
                        for (int o = 0; o < 9; ++o)
                            acc[di][dj][o] += vv * w9[o];
                    }
            }
    }

    // ---- epilogue: idwt2(LL1, LH, HL, HH) -> 4x4 output pixels / color ----
#pragma unroll
    for (int cc = 0; cc < 3; ++cc) {
#pragma unroll
        for (int di = 0; di < 2; ++di) {
            const int I = r0 + 2 * i2 + di;
            const int J = c0 + 2 * j2;
            const float2 llv = *reinterpret_cast<const float2*>(
                LL1 + (((size_t)b * 3 + cc) * 256 + I) * 256 + J);
            float4 top, bot;
            {
                const float ll = llv.x;
                const float lh = acc[di][0][cc * 3 + 0];
                const float hl = acc[di][0][cc * 3 + 1];
                const float hh = acc[di][0][cc * 3 + 2];
                const float e0 = ll + lh, od0 = ll - lh;
                const float e1 = hl + hh, od1 = hl - hh;
                top.x = (e0 + e1) * 0.5f; top.y = (e0 - e1) * 0.5f;
                bot.x = (od0 + od1) * 0.5f; bot.y = (od0 - od1) * 0.5f;
            }
            {
                const float ll = llv.y;
                const float lh = acc[di][1][cc * 3 + 0];
                const float hl = acc[di][1][cc * 3 + 1];
                const float hh = acc[di][1][cc * 3 + 2];
                const float e0 = ll + lh, od0 = ll - lh;
                const float e1 = hl + hh, od1 = hl - hh;
                top.z = (e0 + e1) * 0.5f; top.w = (e0 - e1) * 0.5f;
                bot.z = (od0 + od1) * 0.5f; bot.w = (od0 - od1) * 0.5f;
            }
            float* op = out + (((size_t)b * 3 + cc) * 512 + 2 * I) * 512 + 2 * J;
            *reinterpret_cast<float4*>(op) = top;
            *reinterpret_cast<float4*>(op + 512) = bot;
        }
    }
}

extern "C" void kernel_launch(void* const* d_in, const int* in_sizes, int n_in,
                              void* d_out, int out_size, void* d_ws, size_t ws_size,
                              hipStream_t stream) {
    const float* x  = (const float*)d_in[0];
    const float* dw = (const float*)d_in[1];
    const float* db = (const float*)d_in[2];
    const float* uw = (const float*)d_in[3];
    const float* ub = (const float*)d_in[4];
    float* outp = (float*)d_out;

    float* wsf = (float*)d_ws;
    float* wd  = wsf;            // 729 floats (pad to 768)
    float* wu  = wsf + 768;      // 1296 floats
    float* LL1 = wsf + 2304;                         // 25.2 MB
    float* y   = LL1 + (size_t)BB * 3 * 256 * 256;   // 18.9 MB

    k0_rearrange<<<dim3(1), dim3(256), 0, stream>>>(dw, uw, wd, wu);
    k1_dwt_down<<<dim3(4096), dim3(256), 0, stream>>>(x, wd, db, LL1, y);
    k2_up_idwt<<<dim3(BB * 64), dim3(256), 0, stream>>>(y, wu, ub, LL1, outp);
}